// Round 6
// baseline (4572.240 us; speedup 1.0000x reference)
//
#include <hip/hip_runtime.h>
#include <hip/hip_bf16.h>
#include <cstdint>
#include <cstddef>

typedef short short8 __attribute__((ext_vector_type(8)));
typedef float f32x4 __attribute__((ext_vector_type(4)));
typedef unsigned long long u64;
typedef unsigned int u32;

#define TT 512
#define BB 64
#define DD 1024
#define LL 1024

// ---------------------------------------------------------------------------
// Prep 1: transpose + convert 4 gate weights [2048,1024] fp32 -> Wt[c][k] bf16,
// c = g*1024 + l, k contiguous. (Verified R0/R1/R3/R4/R5.)
// ---------------------------------------------------------------------------
__global__ __launch_bounds__(256) void transpose_w(
    const float* __restrict__ Wf, const float* __restrict__ Wi,
    const float* __restrict__ Wo, const float* __restrict__ Wg,
    __hip_bfloat16* __restrict__ Wt) {
  __shared__ float tile[32][33];
  const int g = blockIdx.z;
  const float* W = (g == 0) ? Wf : (g == 1) ? Wi : (g == 2) ? Wo : Wg;
  const int k0 = blockIdx.x * 32, l0 = blockIdx.y * 32;
  const int c = threadIdx.x & 31, r0 = threadIdx.x >> 5;
#pragma unroll
  for (int rr = 0; rr < 4; ++rr) {
    const int kk = r0 + rr * 8;
    tile[kk][c] = W[(size_t)(k0 + kk) * LL + (l0 + c)];
  }
  __syncthreads();
#pragma unroll
  for (int rr = 0; rr < 4; ++rr) {
    const int ll = r0 + rr * 8;
    Wt[((size_t)(g * LL + l0 + ll) << 11) + (k0 + c)] = __float2bfloat16(tile[c][ll]);
  }
}

// ---------------------------------------------------------------------------
// Prep 2: x fp32 -> bf16.
// ---------------------------------------------------------------------------
__global__ __launch_bounds__(256) void xconv(const float* __restrict__ x,
                                             __hip_bfloat16* __restrict__ xbf) {
  const size_t i = (size_t)blockIdx.x * 256 + threadIdx.x;
  const float4 v = ((const float4*)x)[i];
  union { __hip_bfloat16 b[4]; uint2 u; } o;
  o.b[0] = __float2bfloat16(v.x);
  o.b[1] = __float2bfloat16(v.y);
  o.b[2] = __float2bfloat16(v.z);
  o.b[3] = __float2bfloat16(v.w);
  ((uint2*)xbf)[i] = o.u;
}

// ---------------------------------------------------------------------------
// PERSISTENT LSTM v6 — v5 structure + single-epoch-counter sync.
// 256 blocks (1/CU) x 512 thr. Waves 0-3: h-GEMM + pointwise + stores.
// Waves 4-7: x-GEMM one step ahead -> gsx double buffer. Weights in LDS.
// Sync per step: h sc1 stores -> vmcnt(0) -> __syncthreads -> tid0
// atomic_add(ctr,1) [L3, one line] -> out stores (off critical path).
// Readers: wave0 lane0 hot-polls ctr >= 256*t (one 4B sc1 load, no sleep,
// dependent-load latency = natural backoff), LDS ep broadcast to waves 1-3.
// Virgin per-step h buffers: sc1 write-through, plain cached reads (proven
// v4/v5). All spins bounded: failure = wrong numbers, never a hang.
// ---------------------------------------------------------------------------
__global__ __launch_bounds__(512, 2) void lstm_persist(
    const __hip_bfloat16* __restrict__ xbf, const __hip_bfloat16* __restrict__ Wt,
    const float* __restrict__ bfv, const float* __restrict__ biv,
    const float* __restrict__ bov, const float* __restrict__ bgv,
    float* __restrict__ out, __hip_bfloat16* __restrict__ hball,
    int* __restrict__ ctr) {
  __shared__ short8 wf[4096];       // 64 KB weights: [kp][frag j][lane]
  __shared__ float gw[4][16][17];   // per-h-wave gate transpose tile
  __shared__ float gsx[2][64][17];  // x-partial double buffer
  __shared__ int ep;

  const int tid = threadIdx.x;
  const int lane = tid & 63, w = tid >> 6;
  const int quad = lane >> 4, hc = lane & 15;
  const bool isH = (w < 4);
  const int bt = w & 3;
  const int kp = isH ? 1 : 0;
  const int bid = blockIdx.x;
  const int l0 = bid * 4;

  if (tid == 0) ep = 0;

  // ---- stage weights into LDS (wave0: kp=1 half, wave4: kp=0 half) ----
  const int col = ((hc >> 2) << 10) + l0 + (hc & 3);
  if (w == 0 || w == 4) {
    const __hip_bfloat16* wb = Wt + ((size_t)col << 11) + (kp << 10) + quad * 8;
#pragma unroll
    for (int j = 0; j < 32; ++j)
      wf[(kp << 11) + (j << 6) + lane] = *(const short8*)(wb + j * 32);
  }

  const int rowoff = (bt << 4) + hc;  // batch row this lane loads (A-frag)

  // ---- pointwise state (h-waves): lane -> (b = bt*16+row16, l = l0+lc) ----
  const int row16 = lane >> 2, lc = lane & 3;
  const int pl = l0 + lc;
  float cr = 0.f, bfr = 0.f, bir = 0.f, bor = 0.f, bgr = 0.f;
  if (isH) { bfr = bfv[pl]; bir = biv[pl]; bor = bov[pl]; bgr = bgv[pl]; }

  __syncthreads();  // weights staged, ep init visible

  // x-GEMM for step tt -> gsx[tt&1]  (runs on waves 4-7)
  auto xgemm = [&](int tt) {
    const __hip_bfloat16* za =
        xbf + ((size_t)tt << 16) + ((size_t)rowoff << 10) + quad * 8;
    f32x4 a0 = {}, a1 = {};
    short8 Af[2][8];
#pragma unroll
    for (int i = 0; i < 8; ++i) Af[0][i] = *(const short8*)(za + i * 32);
#pragma unroll
    for (int g = 0; g < 4; ++g) {
      const int cur = g & 1, nxt = cur ^ 1;
      if (g < 3) {
#pragma unroll
        for (int i = 0; i < 8; ++i)
          Af[nxt][i] = *(const short8*)(za + (g + 1) * 256 + i * 32);
      }
#pragma unroll
      for (int i = 0; i < 8; ++i) {
        const short8 bb = wf[((g << 3) + i) * 64 + lane];  // kp=0 base
        if (i & 1)
          a1 = __builtin_amdgcn_mfma_f32_16x16x32_bf16(Af[cur][i], bb, a1, 0, 0, 0);
        else
          a0 = __builtin_amdgcn_mfma_f32_16x16x32_bf16(Af[cur][i], bb, a0, 0, 0, 0);
      }
    }
    const int par = tt & 1;
#pragma unroll
    for (int r = 0; r < 4; ++r)
      gsx[par][(bt << 4) + (quad << 2) + r][hc] = a0[r] + a1[r];
  };

  if (!isH) xgemm(0);  // prologue: x-partial for step 0
  __syncthreads();

  for (int t = 0; t < TT; ++t) {
    float hval = 0.f;
    int b = 0;

    if (!isH) {
      // ---- x prefetch for step t+1 (off critical path) ----
      if (t + 1 < TT) xgemm(t + 1);
    } else {
      f32x4 a0 = {}, a1 = {};
      if (t > 0) {
        // ---- wait for step t-1: wave0 lane0 hot-polls epoch counter ----
        if (w == 0) {
          if (lane == 0) {
            const int want = t << 8;  // 256 * t
            int spins = 0;
            while (__hip_atomic_load(ctr, __ATOMIC_RELAXED,
                                     __HIP_MEMORY_SCOPE_AGENT) < want) {
              if (++spins > (1 << 20)) break;  // fail visible, never hang
            }
            __hip_atomic_store(&ep, t, __ATOMIC_RELAXED,
                               __HIP_MEMORY_SCOPE_WORKGROUP);
          }
          // wave0 lanes reconverge; ep ds-spin below covers lanes 1-63 too
        }
        {
          int spins = 0;
          while (__hip_atomic_load(&ep, __ATOMIC_RELAXED,
                                   __HIP_MEMORY_SCOPE_WORKGROUP) < t) {
            if (++spins > (1 << 24)) break;  // fail visible, never hang
          }
        }
        asm volatile("" ::: "memory");  // keep h loads below the spin

        // ---- h-GEMM: plain cached u64 loads from virgin h[t-1] ----
        const u64* hp = (const u64*)(hball + ((size_t)(t - 1) << 16)) +
                        (quad << 7) + rowoff;
        union frag { short8 s; u64 u[2]; };
        frag Ah[2][8];
#pragma unroll
        for (int i = 0; i < 8; ++i) {
          Ah[0][i].u[0] = hp[i * 512];
          Ah[0][i].u[1] = hp[i * 512 + 64];
        }
#pragma unroll
        for (int g = 0; g < 4; ++g) {
          const int cur = g & 1, nxt = cur ^ 1;
          if (g < 3) {
#pragma unroll
            for (int i = 0; i < 8; ++i) {
              Ah[nxt][i].u[0] = hp[(g + 1) * 4096 + i * 512];
              Ah[nxt][i].u[1] = hp[(g + 1) * 4096 + i * 512 + 64];
            }
          }
#pragma unroll
          for (int i = 0; i < 8; ++i) {
            const short8 bb = wf[2048 + ((g << 3) + i) * 64 + lane];  // kp=1
            if (i & 1)
              a1 = __builtin_amdgcn_mfma_f32_16x16x32_bf16(Ah[cur][i].s, bb, a1, 0, 0, 0);
            else
              a0 = __builtin_amdgcn_mfma_f32_16x16x32_bf16(Ah[cur][i].s, bb, a0, 0, 0, 0);
          }
        }
      }

      // ---- gw = h-partial + x-partial (wave-local transpose tile) ----
#pragma unroll
      for (int r = 0; r < 4; ++r)
        gw[bt][(quad << 2) + r][hc] =
            a0[r] + a1[r] + gsx[t & 1][(bt << 4) + (quad << 2) + r][hc];

      // ---- pointwise (same wave; in-wave LDS ordering only) ----
      const float fp = gw[bt][row16][lc] + bfr;
      const float ip = gw[bt][row16][4 + lc] + bir;
      const float op = gw[bt][row16][8 + lc] + bor;
      const float gp = gw[bt][row16][12 + lc] + bgr;
      const float fs = 1.0f / (1.0f + __expf(-fp));
      const float is = 1.0f / (1.0f + __expf(-ip));
      const float os = 1.0f / (1.0f + __expf(-op));
      const float gv = tanhf(gp);
      cr = fs * cr + is * gv;
      hval = os * tanhf(cr);
      b = (bt << 4) + row16;

      // ---- h publish store FIRST (sc1 write-through, block-major chunk) ----
      const float hn = __shfl_xor(hval, 1);
      if ((lc & 1) == 0) {
        union { __hip_bfloat16 x[2]; u32 u; } hu;
        hu.x[0] = __float2bfloat16(hval);
        hu.x[1] = __float2bfloat16(hn);
        u32* hwp = (u32*)(hball + ((size_t)t << 16));
        __hip_atomic_store(hwp + (bid << 7) + (b << 1) + (lc >> 1), hu.u,
                           __ATOMIC_RELAXED, __HIP_MEMORY_SCOPE_AGENT);
      }
    }

    asm volatile("s_waitcnt vmcnt(0)" ::: "memory");  // h committed to L3
    __syncthreads();                                  // all waves drained + gsx handoff
    if (tid == 0)
      __hip_atomic_fetch_add(ctr, 1, __ATOMIC_RELAXED,
                             __HIP_MEMORY_SCOPE_AGENT);

    // ---- out store AFTER publish: drains under next step's spin window ----
    if (isH)
      out[((size_t)t << 16) + ((size_t)b << 10) + pl] = hval;
  }
}

// ---------------------------------------------------------------------------
extern "C" void kernel_launch(void* const* d_in, const int* in_sizes, int n_in,
                              void* d_out, int out_size, void* d_ws, size_t ws_size,
                              hipStream_t stream) {
  const float* x   = (const float*)d_in[0];
  const float* Wf  = (const float*)d_in[1];
  const float* bfv = (const float*)d_in[2];
  const float* Wi  = (const float*)d_in[3];
  const float* biv = (const float*)d_in[4];
  const float* Wo  = (const float*)d_in[5];
  const float* bov = (const float*)d_in[6];
  const float* Wg  = (const float*)d_in[7];
  const float* bgv = (const float*)d_in[8];
  float* out = (float*)d_out;

  // ws: Wt 16MB | xbf 64MB | hball 64MB (512 virgin 128KB h buffers) | ctr 1KB
  __hip_bfloat16* Wt    = (__hip_bfloat16*)d_ws;
  __hip_bfloat16* xbf   = Wt + (size_t)4096 * 2048;
  __hip_bfloat16* hball = xbf + (size_t)TT * BB * LL;
  int* ctr = (int*)(hball + (size_t)TT * 65536);

  transpose_w<<<dim3(64, 32, 4), 256, 0, stream>>>(Wf, Wi, Wo, Wg, Wt);
  xconv<<<dim3((TT * BB * LL) / 4 / 256), 256, 0, stream>>>(x, xbf);
  hipMemsetAsync(ctr, 0, 256 * sizeof(int), stream);

  lstm_persist<<<256, 512, 0, stream>>>(xbf, Wt, bfv, biv, bov, bgv,
                                        out, hball, ctr);
}